// Round 2
// baseline (3987.276 us; speedup 1.0000x reference)
//
#include <hip/hip_runtime.h>
#include <hip/hip_bf16.h>
#include <math.h>

// CodeGenAttention: B=2, S=2048, H=4096, NH=16, D=256, ROT=64, MP=4
// Reference dtypes are fp32; dataset may have downcast to bf16. We detect at
// runtime (flag in ws) and branch global-load/store paths uniformly.

typedef __attribute__((ext_vector_type(8))) short bf16x8;
typedef __attribute__((ext_vector_type(4))) float f32x4;
typedef unsigned short u16;

__device__ __forceinline__ u16 f2b(float f) {
    __hip_bfloat16 h = __float2bfloat16(f);
    return *reinterpret_cast<u16*>(&h);
}
__device__ __forceinline__ float b2f(u16 u) {
    __hip_bfloat16 h = *reinterpret_cast<__hip_bfloat16*>(&u);
    return __bfloat162float(h);
}

// ---------------- dtype probe: fp32 data read as bf16 halves has wild
// exponent fields (>=0xC0); true bf16 N(0,1) data never does. -------------
__global__ void detect_kernel(const u16* __restrict__ h, int* __restrict__ flag)
{
    int lane = threadIdx.x & 63;
    int cnt = 0;
    for (int i = lane; i < 8192; i += 64) {
        int e = (h[i] >> 7) & 0xFF;
        cnt += (e >= 0xC0);
    }
    for (int off = 32; off > 0; off >>= 1) cnt += __shfl_down(cnt, off, 64);
    if (lane == 0) *flag = (cnt > 0) ? 1 : 0;
}

// ---------------- GEMM: C[M,N] = A[M,K] @ B[K,N] --------------------------
// block 256 (4 waves), tile 128x128x32. A dtype: bf16 or (a_dyn && fp32).
// B dtype follows flag. mode 0: plain store (fp32 or bf16 per c_dyn&flag).
// mode 1: qkv scatter into C0=Q, Ck=K, Cv=V laid out [B=2,NH=16,S=2048,D=256].
#define LDT 40  // 32 + 8 pad, keeps 16B alignment

__global__ __launch_bounds__(256)
void gemm_kernel(const void* __restrict__ Av, const void* __restrict__ Bv,
                 const int* __restrict__ flag,
                 int M, int N, int K, int mode, int a_dyn, int c_dyn,
                 u16* __restrict__ C0, u16* __restrict__ Ck, u16* __restrict__ Cv,
                 float* __restrict__ C0f)
{
    __shared__ u16 As[128][LDT];   // As[m][k]
    __shared__ u16 Bs[128][LDT];   // Bs[n][k]  (transposed during staging)

    const int isF32 = *flag;
    const int tid  = threadIdx.x;
    const int wave = tid >> 6, lane = tid & 63;
    const int l15  = lane & 15, quad = lane >> 4;
    const int wr   = wave >> 1, wc = wave & 1;
    const int m0   = blockIdx.y * 128, n0 = blockIdx.x * 128;

    f32x4 acc[4][4];
#pragma unroll
    for (int i = 0; i < 4; i++)
#pragma unroll
        for (int j = 0; j < 4; j++) acc[i][j] = (f32x4){0.f, 0.f, 0.f, 0.f};

    for (int k0 = 0; k0 < K; k0 += 32) {
        // ---- stage A: 128 rows x 32 k
        if (a_dyn && isF32) {
            const float* A = (const float*)Av;
#pragma unroll
            for (int cc = 0; cc < 4; cc++) {
                int ch = tid + cc * 256;           // 1024 chunks of 4 floats
                int r = ch >> 3, c = ch & 7;
                f32x4 v = *reinterpret_cast<const f32x4*>(&A[(size_t)(m0 + r) * K + k0 + c * 4]);
#pragma unroll
                for (int j = 0; j < 4; j++) As[r][c * 4 + j] = f2b(v[j]);
            }
        } else {
            const u16* A = (const u16*)Av;
#pragma unroll
            for (int cc = 0; cc < 2; cc++) {
                int ch = tid + cc * 256;           // 512 chunks of 8 bf16
                int r = ch >> 2, c = ch & 3;
                *reinterpret_cast<uint4*>(&As[r][c * 8]) =
                    *reinterpret_cast<const uint4*>(&A[(size_t)(m0 + r) * K + k0 + c * 8]);
            }
        }
        // ---- stage B transposed: 32 k-rows x 128 n
        if (isF32) {
            const float* Bm = (const float*)Bv;
#pragma unroll
            for (int cc = 0; cc < 4; cc++) {
                int ch = tid + cc * 256;           // 1024 chunks of 4 floats
                int r = ch >> 5, c = ch & 31;
                f32x4 v = *reinterpret_cast<const f32x4*>(&Bm[(size_t)(k0 + r) * N + n0 + c * 4]);
#pragma unroll
                for (int j = 0; j < 4; j++) Bs[c * 4 + j][r] = f2b(v[j]);
            }
        } else {
            const u16* Bm = (const u16*)Bv;
#pragma unroll
            for (int cc = 0; cc < 2; cc++) {
                int ch = tid + cc * 256;           // 512 chunks of 8 bf16
                int r = ch >> 4, c = ch & 15;
                uint4 vb = *reinterpret_cast<const uint4*>(&Bm[(size_t)(k0 + r) * N + n0 + c * 8]);
                const u16* e = reinterpret_cast<const u16*>(&vb);
#pragma unroll
                for (int j = 0; j < 8; j++) Bs[c * 8 + j][r] = e[j];
            }
        }
        __syncthreads();

        bf16x8 aF[4], bF[4];
#pragma unroll
        for (int i = 0; i < 4; i++)
            aF[i] = *reinterpret_cast<const bf16x8*>(&As[wr * 64 + i * 16 + l15][quad * 8]);
#pragma unroll
        for (int j = 0; j < 4; j++)
            bF[j] = *reinterpret_cast<const bf16x8*>(&Bs[wc * 64 + j * 16 + l15][quad * 8]);
#pragma unroll
        for (int i = 0; i < 4; i++)
#pragma unroll
            for (int j = 0; j < 4; j++)
                acc[i][j] = __builtin_amdgcn_mfma_f32_16x16x32_bf16(aF[i], bF[j], acc[i][j], 0, 0, 0);
        __syncthreads();
    }

    if (mode == 0) {
#pragma unroll
        for (int j = 0; j < 4; j++) {
            int n = n0 + wc * 64 + j * 16 + l15;
#pragma unroll
            for (int i = 0; i < 4; i++) {
                int m = m0 + wr * 64 + i * 16 + quad * 4;
#pragma unroll
                for (int r = 0; r < 4; r++) {
                    float v = acc[i][j][r];
                    if (!isfinite(v)) v = 1024.0f;   // diagnostic canary
                    if (c_dyn && isF32) C0f[(size_t)(m + r) * N + n] = v;
                    else                C0[(size_t)(m + r) * N + n] = f2b(v);
                }
            }
        }
    } else {
        // fused_qkv col n -> (mp group g, third t in {q,v,k}, head, d)
#pragma unroll
        for (int j = 0; j < 4; j++) {
            int n = n0 + wc * 64 + j * 16 + l15;
            int g = n / 3072;
            int r3 = n - g * 3072;
            int t = r3 >> 10;            // 0=q, 1=v, 2=k  (reference split order!)
            int r1 = r3 & 1023;
            int head = g * 4 + (r1 >> 8);
            int d = r1 & 255;
            u16* dst = (t == 0) ? C0 : (t == 1) ? Cv : Ck;
            int colbase = head * 2048 * 256 + d;
#pragma unroll
            for (int i = 0; i < 4; i++) {
                int m = m0 + wr * 64 + i * 16 + quad * 4;
#pragma unroll
                for (int r = 0; r < 4; r++) {
                    int mm = m + r;
                    int bb = mm >> 11, s = mm & 2047;
                    dst[(size_t)bb * 8388608 + (size_t)s * 256 + colbase] = f2b(acc[i][j][r]);
                }
            }
        }
    }
}

// ---------------- RoPE (in-place on Q,K first 64 dims, interleaved pairs) --
__global__ __launch_bounds__(256)
void rope_kernel(u16* __restrict__ Q, u16* __restrict__ Kb, const int* __restrict__ pos_ids)
{
    int idx = blockIdx.x * 256 + threadIdx.x;   // 2^21 threads: (b,h,s,pair)
    int i = idx & 31;
    int s = (idx >> 5) & 2047;
    int h = (idx >> 16) & 15;
    int b = idx >> 20;
    int pos = pos_ids[b * 2048 + s];
    float freq = __expf(-(float)(2 * i) * (9.210340371976184f / 64.0f)); // 10000^(-2i/64)
    float ang = (float)pos * freq;
    float sn = sinf(ang), cs = cosf(ang);       // full range reduction (ang up to ~2047)
    size_t base = ((size_t)(b * 16 + h) * 2048 + s) * 256 + 2 * i;
    float q0 = b2f(Q[base]), q1 = b2f(Q[base + 1]);
    Q[base]     = f2b(q0 * cs - q1 * sn);
    Q[base + 1] = f2b(q1 * cs + q0 * sn);
    float k0 = b2f(Kb[base]), k1 = b2f(Kb[base + 1]);
    Kb[base]     = f2b(k0 * cs - k1 * sn);
    Kb[base + 1] = f2b(k1 * cs + k0 * sn);
}

// ---------------- Flash attention (causal), one block = 64 q rows of (b,h) -
__global__ __launch_bounds__(256)
void attn_kernel(const u16* __restrict__ Q, const u16* __restrict__ Kb,
                 const u16* __restrict__ V, u16* __restrict__ att)
{
    __shared__ u16 Ks[32][264];      // [k][d], pad 8
    __shared__ u16 Vts[256][LDT];    // [d][k], pad 8
    __shared__ u16 Ps[4][16][LDT];   // per-wave P tile [q][k]

    const int tid = threadIdx.x;
    const int wave = tid >> 6, lane = tid & 63;
    const int l15 = lane & 15, quad = lane >> 4;
    const int bh = blockIdx.y;
    const int b = bh >> 4, h = bh & 15;
    const int q0 = blockIdx.x * 64;
    const int qrow = q0 + wave * 16;

    const u16* qb = Q + (size_t)bh * 2048 * 256;
    const u16* kb = Kb + (size_t)bh * 2048 * 256;
    const u16* vb = V + (size_t)bh * 2048 * 256;

    bf16x8 qf[8];
#pragma unroll
    for (int ks = 0; ks < 8; ks++)
        qf[ks] = *reinterpret_cast<const bf16x8*>(&qb[(size_t)(qrow + l15) * 256 + ks * 32 + quad * 8]);

    f32x4 O[16];
#pragma unroll
    for (int dt = 0; dt < 16; dt++) O[dt] = (f32x4){0.f, 0.f, 0.f, 0.f};
    float m_run[4] = {-1e30f, -1e30f, -1e30f, -1e30f};
    float l_run[4] = {0.f, 0.f, 0.f, 0.f};
    const float scale = 1.0f / 16.0f;   // 1/sqrt(256)

    const int nkt = (q0 >> 5) + 2;      // causal: tiles with k0 <= q0+63
    for (int kt = 0; kt < nkt; kt++) {
        int k0 = kt * 32;
#pragma unroll
        for (int cc = 0; cc < 4; cc++) {            // stage K [32][256]
            int ch = tid + cc * 256;
            int r = ch >> 5, c = ch & 31;
            *reinterpret_cast<uint4*>(&Ks[r][c * 8]) =
                *reinterpret_cast<const uint4*>(&kb[(size_t)(k0 + r) * 256 + c * 8]);
        }
#pragma unroll
        for (int cc = 0; cc < 4; cc++) {            // stage V transposed
            int ch = tid + cc * 256;
            int r = ch >> 5, c = ch & 31;
            uint4 vv = *reinterpret_cast<const uint4*>(&vb[(size_t)(k0 + r) * 256 + c * 8]);
            const u16* e = reinterpret_cast<const u16*>(&vv);
#pragma unroll
            for (int j = 0; j < 8; j++) Vts[c * 8 + j][r] = e[j];
        }
        __syncthreads();

        // S = Q K^T  (two 16-col tiles)
        f32x4 sc[2];
#pragma unroll
        for (int nt = 0; nt < 2; nt++) {
            sc[nt] = (f32x4){0.f, 0.f, 0.f, 0.f};
#pragma unroll
            for (int ks = 0; ks < 8; ks++) {
                bf16x8 kf = *reinterpret_cast<const bf16x8*>(&Ks[nt * 16 + l15][ks * 32 + quad * 8]);
                sc[nt] = __builtin_amdgcn_mfma_f32_16x16x32_bf16(qf[ks], kf, sc[nt], 0, 0, 0);
            }
        }
        // scale + causal mask + online softmax (rows = quad*4+r, cols = l15)
        float p[2][4], mloc[4], alpha[4], sum[4];
#pragma unroll
        for (int r = 0; r < 4; r++) {
            int qg = qrow + quad * 4 + r;
#pragma unroll
            for (int nt = 0; nt < 2; nt++) {
                int kg = k0 + nt * 16 + l15;
                float v = sc[nt][r] * scale;
                p[nt][r] = (kg <= qg) ? v : -1e30f;
            }
            mloc[r] = fmaxf(p[0][r], p[1][r]);
        }
#pragma unroll
        for (int off = 1; off < 16; off <<= 1)
#pragma unroll
            for (int r = 0; r < 4; r++)
                mloc[r] = fmaxf(mloc[r], __shfl_xor(mloc[r], off, 16));
#pragma unroll
        for (int r = 0; r < 4; r++) {
            float mnew = fmaxf(m_run[r], mloc[r]);
            alpha[r] = __expf(m_run[r] - mnew);
            p[0][r] = __expf(p[0][r] - mnew);
            p[1][r] = __expf(p[1][r] - mnew);
            sum[r] = p[0][r] + p[1][r];
            m_run[r] = mnew;
        }
#pragma unroll
        for (int off = 1; off < 16; off <<= 1)
#pragma unroll
            for (int r = 0; r < 4; r++)
                sum[r] += __shfl_xor(sum[r], off, 16);
#pragma unroll
        for (int r = 0; r < 4; r++) l_run[r] = l_run[r] * alpha[r] + sum[r];
#pragma unroll
        for (int dt = 0; dt < 16; dt++)
#pragma unroll
            for (int r = 0; r < 4; r++) O[dt][r] *= alpha[r];

        // P: C-layout -> A-layout via per-wave LDS round-trip
#pragma unroll
        for (int nt = 0; nt < 2; nt++)
#pragma unroll
            for (int r = 0; r < 4; r++)
                Ps[wave][quad * 4 + r][nt * 16 + l15] = f2b(p[nt][r]);
        bf16x8 aP = *reinterpret_cast<const bf16x8*>(&Ps[wave][l15][quad * 8]);

        // O += P V
#pragma unroll
        for (int dt = 0; dt < 16; dt++) {
            bf16x8 vf = *reinterpret_cast<const bf16x8*>(&Vts[dt * 16 + l15][quad * 8]);
            O[dt] = __builtin_amdgcn_mfma_f32_16x16x32_bf16(aP, vf, O[dt], 0, 0, 0);
        }
        __syncthreads();
    }

    float inv[4];
#pragma unroll
    for (int r = 0; r < 4; r++) inv[r] = 1.0f / l_run[r];
#pragma unroll
    for (int dt = 0; dt < 16; dt++)
#pragma unroll
        for (int r = 0; r < 4; r++) {
            int s = qrow + quad * 4 + r;
            att[((size_t)b * 2048 + s) * 4096 + h * 256 + dt * 16 + l15] = f2b(O[dt][r] * inv[r]);
        }
}

extern "C" void kernel_launch(void* const* d_in, const int* in_sizes, int n_in,
                              void* d_out, int out_size, void* d_ws, size_t ws_size,
                              hipStream_t stream)
{
    const void* hidden  = d_in[0];
    const int*  pos_ids = (const int*)d_in[1];
    // d_in[2] attention_mask: all-true -> only causal mask matters
    const void* w_qkv   = d_in[3];
    const void* w_out   = d_in[4];

    char* ws = (char*)d_ws;
    int* flag = (int*)ws;                         // 256 B slot
    u16* qbuf = (u16*)(ws + 256);                 // [2,16,2048,256] bf16 = 32 MiB
    u16* kbuf = (u16*)(ws + 256 + 33554432);
    u16* vbuf = (u16*)(ws + 256 + 67108864);
    u16* att  = (u16*)(ws + 256 + 100663296);     // [2,2048,4096] bf16 = 32 MiB

    detect_kernel<<<1, 64, 0, stream>>>((const u16*)hidden, flag);

    dim3 g1(12288 / 128, 4096 / 128);             // QKV GEMM + scatter epilogue
    gemm_kernel<<<g1, 256, 0, stream>>>(hidden, w_qkv, flag, 4096, 12288, 4096,
                                        /*mode*/1, /*a_dyn*/1, /*c_dyn*/0,
                                        qbuf, kbuf, vbuf, nullptr);
    rope_kernel<<<8192, 256, 0, stream>>>(qbuf, kbuf, pos_ids);
    dim3 ga(32, 32);                              // (q-tiles, b*h)
    attn_kernel<<<ga, 256, 0, stream>>>(qbuf, kbuf, vbuf, att);
    dim3 g2(4096 / 128, 4096 / 128);              // out-proj GEMM
    gemm_kernel<<<g2, 256, 0, stream>>>(att, w_out, flag, 4096, 4096, 4096,
                                        /*mode*/0, /*a_dyn*/0, /*c_dyn*/1,
                                        (u16*)d_out, nullptr, nullptr, (float*)d_out);
}

// Round 3
// 2532.413 us; speedup vs baseline: 1.5745x; 1.5745x over previous
//
#include <hip/hip_runtime.h>
#include <hip/hip_bf16.h>
#include <math.h>
#include <stdint.h>

// CodeGenAttention: B=2, S=2048, H=4096, NH=16, D=256, ROT=64, MP=4
// Inputs detected fp32 (runtime flag kept for robustness). Pipeline:
//  detect -> convert hidden->bf16 -> transpose+convert W's -> bf16 MFMA GEMMs
//  (m97-style global_load_lds staging) -> rope -> flash attn -> out GEMM.

typedef __attribute__((ext_vector_type(8))) short bf16x8;
typedef __attribute__((ext_vector_type(4))) float f32x4;
typedef unsigned short u16;

__device__ __forceinline__ u16 f2b(float f) {
    __hip_bfloat16 h = __float2bfloat16(f);
    return *reinterpret_cast<u16*>(&h);
}
__device__ __forceinline__ float b2f(u16 u) {
    __hip_bfloat16 h = *reinterpret_cast<__hip_bfloat16*>(&u);
    return __bfloat162float(h);
}

__device__ __forceinline__ void load_lds16(const u16* g, u16* l) {
    __builtin_amdgcn_global_load_lds((const __attribute__((address_space(1))) void*)g,
                                     (__attribute__((address_space(3))) void*)l, 16, 0, 0);
}

// ---------------- dtype probe ---------------------------------------------
__global__ void detect_kernel(const u16* __restrict__ h, int* __restrict__ flag)
{
    int lane = threadIdx.x & 63;
    int cnt = 0;
    for (int i = lane; i < 8192; i += 64) {
        int e = (h[i] >> 7) & 0xFF;
        cnt += (e >= 0xC0);
    }
    for (int off = 32; off > 0; off >>= 1) cnt += __shfl_down(cnt, off, 64);
    if (lane == 0) *flag = (cnt > 0) ? 1 : 0;
}

// ---------------- elementwise convert to bf16 (8 elems/thread) ------------
__global__ __launch_bounds__(256)
void convert_kernel(const void* __restrict__ in, const int* __restrict__ flag,
                    u16* __restrict__ outp, int n8)
{
    int idx = blockIdx.x * 256 + threadIdx.x;
    if (idx >= n8) return;
    if (*flag) {
        const float* x = (const float*)in;
        f32x4 a = *reinterpret_cast<const f32x4*>(&x[(size_t)idx * 8]);
        f32x4 b = *reinterpret_cast<const f32x4*>(&x[(size_t)idx * 8 + 4]);
        u16 t[8];
#pragma unroll
        for (int j = 0; j < 4; j++) { t[j] = f2b(a[j]); t[4 + j] = f2b(b[j]); }
        *reinterpret_cast<uint4*>(&outp[(size_t)idx * 8]) = *reinterpret_cast<uint4*>(t);
    } else {
        ((uint4*)outp)[idx] = ((const uint4*)in)[idx];
    }
}

// ---------------- transpose + convert: W[K,N] -> Wt[N,K] bf16 -------------
__global__ __launch_bounds__(256)
void transpose_conv_kernel(const void* __restrict__ Wv, const int* __restrict__ flag,
                           int K, int N, u16* __restrict__ Wt)
{
    __shared__ u16 T[64][68];   // pitch 68: row 136 B (8B aligned), low write conflicts
    const int tid = threadIdx.x;
    const int k0 = blockIdx.y * 64, n0 = blockIdx.x * 64;
    const int kr = tid >> 4, nc = tid & 15;
    if (*flag) {
        const float* W = (const float*)Wv;
#pragma unroll
        for (int kk = 0; kk < 4; kk++) {
            int k = kr + kk * 16;
            f32x4 v = *reinterpret_cast<const f32x4*>(&W[(size_t)(k0 + k) * N + n0 + nc * 4]);
#pragma unroll
            for (int j = 0; j < 4; j++) T[nc * 4 + j][k] = f2b(v[j]);
        }
    } else {
        const u16* W = (const u16*)Wv;
#pragma unroll
        for (int kk = 0; kk < 4; kk++) {
            int k = kr + kk * 16;
            ushort4 v = *reinterpret_cast<const ushort4*>(&W[(size_t)(k0 + k) * N + n0 + nc * 4]);
            T[nc * 4 + 0][k] = v.x; T[nc * 4 + 1][k] = v.y;
            T[nc * 4 + 2][k] = v.z; T[nc * 4 + 3][k] = v.w;
        }
    }
    __syncthreads();
#pragma unroll
    for (int it = 0; it < 2; it++) {
        int ch = tid + it * 256;
        int n = ch >> 3, kc = ch & 7;
        const uint2* s2 = reinterpret_cast<const uint2*>(&T[n][kc * 8]); // 8B aligned
        uint2 a = s2[0], b = s2[1];
        uint4 o; o.x = a.x; o.y = a.y; o.z = b.x; o.w = b.y;
        *reinterpret_cast<uint4*>(&Wt[(size_t)(n0 + n) * K + k0 + kc * 8]) = o;
    }
}

// ---------------- GEMM: C[M,N] = A[M,K] @ Bt[N,K]^T, all bf16 -------------
// m97 structure: 128x128x32 tile, global_load_lds(16B) staging, ds_read_b128.
// mode 0: plain store (fp32/bf16 per flag). mode 1: qkv scatter.
__global__ __launch_bounds__(256)
void gemm_bt_kernel(const u16* __restrict__ A, const u16* __restrict__ Bt,
                    const int* __restrict__ flag,
                    int M, int N, int K, int mode,
                    u16* __restrict__ C0, u16* __restrict__ Ck, u16* __restrict__ Cv,
                    float* __restrict__ C0f)
{
    __shared__ u16 As[128][32];   // 8 KiB, row = 64 B
    __shared__ u16 Bs[128][32];

    const int tid  = threadIdx.x;
    const int wave = tid >> 6, lane = tid & 63;
    const int l15  = lane & 15, quad = lane >> 4;
    const int wr   = wave >> 1, wc = wave & 1;
    const int m0   = blockIdx.y * 128, n0 = blockIdx.x * 128;

    const int rsub = lane >> 2;        // 0..15 row within 16-row chunk
    const int kc8  = (lane & 3) * 8;   // k element offset of this lane's 16B

    f32x4 acc[4][4];
#pragma unroll
    for (int i = 0; i < 4; i++)
#pragma unroll
        for (int j = 0; j < 4; j++) acc[i][j] = (f32x4){0.f, 0.f, 0.f, 0.f};

    for (int k0 = 0; k0 < K; k0 += 32) {
        // async stage: each wave fills 2x16 rows of As and Bs (1024 B per inst)
#pragma unroll
        for (int t = 0; t < 2; t++) {
            int chunk = wave * 2 + t;          // 0..7
            int row = chunk * 16 + rsub;
            load_lds16(&A[(size_t)(m0 + row) * K + k0 + kc8],  &As[0][0] + chunk * 512);
            load_lds16(&Bt[(size_t)(n0 + row) * K + k0 + kc8], &Bs[0][0] + chunk * 512);
        }
        __syncthreads();

        bf16x8 aF[4], bF[4];
#pragma unroll
        for (int i = 0; i < 4; i++)
            aF[i] = *reinterpret_cast<const bf16x8*>(&As[wr * 64 + i * 16 + l15][quad * 8]);
#pragma unroll
        for (int j = 0; j < 4; j++)
            bF[j] = *reinterpret_cast<const bf16x8*>(&Bs[wc * 64 + j * 16 + l15][quad * 8]);
#pragma unroll
        for (int i = 0; i < 4; i++)
#pragma unroll
            for (int j = 0; j < 4; j++)
                acc[i][j] = __builtin_amdgcn_mfma_f32_16x16x32_bf16(aF[i], bF[j], acc[i][j], 0, 0, 0);
        __syncthreads();
    }

    const int isF32 = *flag;
    if (mode == 0) {
#pragma unroll
        for (int j = 0; j < 4; j++) {
            int n = n0 + wc * 64 + j * 16 + l15;
#pragma unroll
            for (int i = 0; i < 4; i++) {
                int m = m0 + wr * 64 + i * 16 + quad * 4;
#pragma unroll
                for (int r = 0; r < 4; r++) {
                    float v = acc[i][j][r];
                    if (isF32) C0f[(size_t)(m + r) * N + n] = v;
                    else       C0[(size_t)(m + r) * N + n] = f2b(v);
                }
            }
        }
    } else {
        // fused_qkv col n -> (mp group g, third t in {q,v,k}, head, d)
#pragma unroll
        for (int j = 0; j < 4; j++) {
            int n = n0 + wc * 64 + j * 16 + l15;
            int g = n / 3072;
            int r3 = n - g * 3072;
            int t = r3 >> 10;            // 0=q, 1=v, 2=k (reference split order)
            int r1 = r3 & 1023;
            int head = g * 4 + (r1 >> 8);
            int d = r1 & 255;
            u16* dst = (t == 0) ? C0 : (t == 1) ? Cv : Ck;
            int colbase = head * 2048 * 256 + d;
#pragma unroll
            for (int i = 0; i < 4; i++) {
                int m = m0 + wr * 64 + i * 16 + quad * 4;
#pragma unroll
                for (int r = 0; r < 4; r++) {
                    int mm = m + r;
                    int bb = mm >> 11, s = mm & 2047;
                    dst[(size_t)bb * 8388608 + (size_t)s * 256 + colbase] = f2b(acc[i][j][r]);
                }
            }
        }
    }
}

// ---------------- RoPE (in-place on Q,K first 64 dims, interleaved pairs) --
__global__ __launch_bounds__(256)
void rope_kernel(u16* __restrict__ Q, u16* __restrict__ Kb, const int* __restrict__ pos_ids)
{
    int idx = blockIdx.x * 256 + threadIdx.x;   // (b,h,s,pair)
    int i = idx & 31;
    int s = (idx >> 5) & 2047;
    int h = (idx >> 16) & 15;
    int b = idx >> 20;
    int pos = pos_ids[b * 2048 + s];
    float freq = __expf(-(float)(2 * i) * (9.210340371976184f / 64.0f)); // 10000^(-2i/64)
    float ang = (float)pos * freq;
    float sn = sinf(ang), cs = cosf(ang);
    size_t base = ((size_t)(b * 16 + h) * 2048 + s) * 256 + 2 * i;
    float q0 = b2f(Q[base]), q1 = b2f(Q[base + 1]);
    Q[base]     = f2b(q0 * cs - q1 * sn);
    Q[base + 1] = f2b(q1 * cs + q0 * sn);
    float k0 = b2f(Kb[base]), k1 = b2f(Kb[base + 1]);
    Kb[base]     = f2b(k0 * cs - k1 * sn);
    Kb[base + 1] = f2b(k1 * cs + k0 * sn);
}

// ---------------- Flash attention (causal), one block = 64 q rows of (b,h) -
#define LDT 40
__global__ __launch_bounds__(256)
void attn_kernel(const u16* __restrict__ Q, const u16* __restrict__ Kb,
                 const u16* __restrict__ V, u16* __restrict__ att)
{
    __shared__ u16 Ks[32][264];      // [k][d], pad 8
    __shared__ u16 Vts[256][LDT];    // [d][k], pad 8
    __shared__ u16 Ps[4][16][LDT];   // per-wave P tile [q][k]

    const int tid = threadIdx.x;
    const int wave = tid >> 6, lane = tid & 63;
    const int l15 = lane & 15, quad = lane >> 4;
    const int bh = blockIdx.y;
    const int b = bh >> 4, h = bh & 15;
    const int q0 = blockIdx.x * 64;
    const int qrow = q0 + wave * 16;

    const u16* qb = Q + (size_t)bh * 2048 * 256;
    const u16* kb = Kb + (size_t)bh * 2048 * 256;
    const u16* vb = V + (size_t)bh * 2048 * 256;

    bf16x8 qf[8];
#pragma unroll
    for (int ks = 0; ks < 8; ks++)
        qf[ks] = *reinterpret_cast<const bf16x8*>(&qb[(size_t)(qrow + l15) * 256 + ks * 32 + quad * 8]);

    f32x4 O[16];
#pragma unroll
    for (int dt = 0; dt < 16; dt++) O[dt] = (f32x4){0.f, 0.f, 0.f, 0.f};
    float m_run[4] = {-1e30f, -1e30f, -1e30f, -1e30f};
    float l_run[4] = {0.f, 0.f, 0.f, 0.f};
    const float scale = 1.0f / 16.0f;

    const int nkt = (q0 >> 5) + 2;
    for (int kt = 0; kt < nkt; kt++) {
        int k0 = kt * 32;
#pragma unroll
        for (int cc = 0; cc < 4; cc++) {            // stage K [32][256]
            int ch = tid + cc * 256;
            int r = ch >> 5, c = ch & 31;
            *reinterpret_cast<uint4*>(&Ks[r][c * 8]) =
                *reinterpret_cast<const uint4*>(&kb[(size_t)(k0 + r) * 256 + c * 8]);
        }
#pragma unroll
        for (int cc = 0; cc < 4; cc++) {            // stage V transposed
            int ch = tid + cc * 256;
            int r = ch >> 5, c = ch & 31;
            uint4 vv = *reinterpret_cast<const uint4*>(&vb[(size_t)(k0 + r) * 256 + c * 8]);
            const u16* e = reinterpret_cast<const u16*>(&vv);
#pragma unroll
            for (int j = 0; j < 8; j++) Vts[c * 8 + j][r] = e[j];
        }
        __syncthreads();

        f32x4 sc[2];
#pragma unroll
        for (int nt = 0; nt < 2; nt++) {
            sc[nt] = (f32x4){0.f, 0.f, 0.f, 0.f};
#pragma unroll
            for (int ks = 0; ks < 8; ks++) {
                bf16x8 kf = *reinterpret_cast<const bf16x8*>(&Ks[nt * 16 + l15][ks * 32 + quad * 8]);
                sc[nt] = __builtin_amdgcn_mfma_f32_16x16x32_bf16(qf[ks], kf, sc[nt], 0, 0, 0);
            }
        }
        float p[2][4], mloc[4], alpha[4], sum[4];
#pragma unroll
        for (int r = 0; r < 4; r++) {
            int qg = qrow + quad * 4 + r;
#pragma unroll
            for (int nt = 0; nt < 2; nt++) {
                int kg = k0 + nt * 16 + l15;
                float v = sc[nt][r] * scale;
                p[nt][r] = (kg <= qg) ? v : -1e30f;
            }
            mloc[r] = fmaxf(p[0][r], p[1][r]);
        }
#pragma unroll
        for (int off = 1; off < 16; off <<= 1)
#pragma unroll
            for (int r = 0; r < 4; r++)
                mloc[r] = fmaxf(mloc[r], __shfl_xor(mloc[r], off, 16));
#pragma unroll
        for (int r = 0; r < 4; r++) {
            float mnew = fmaxf(m_run[r], mloc[r]);
            alpha[r] = __expf(m_run[r] - mnew);
            p[0][r] = __expf(p[0][r] - mnew);
            p[1][r] = __expf(p[1][r] - mnew);
            sum[r] = p[0][r] + p[1][r];
            m_run[r] = mnew;
        }
#pragma unroll
        for (int off = 1; off < 16; off <<= 1)
#pragma unroll
            for (int r = 0; r < 4; r++)
                sum[r] += __shfl_xor(sum[r], off, 16);
#pragma unroll
        for (int r = 0; r < 4; r++) l_run[r] = l_run[r] * alpha[r] + sum[r];
#pragma unroll
        for (int dt = 0; dt < 16; dt++)
#pragma unroll
            for (int r = 0; r < 4; r++) O[dt][r] *= alpha[r];

#pragma unroll
        for (int nt = 0; nt < 2; nt++)
#pragma unroll
            for (int r = 0; r < 4; r++)
                Ps[wave][quad * 4 + r][nt * 16 + l15] = f2b(p[nt][r]);
        bf16x8 aP = *reinterpret_cast<const bf16x8*>(&Ps[wave][l15][quad * 8]);

#pragma unroll
        for (int dt = 0; dt < 16; dt++) {
            bf16x8 vf = *reinterpret_cast<const bf16x8*>(&Vts[dt * 16 + l15][quad * 8]);
            O[dt] = __builtin_amdgcn_mfma_f32_16x16x32_bf16(aP, vf, O[dt], 0, 0, 0);
        }
        __syncthreads();
    }

    float inv[4];
#pragma unroll
    for (int r = 0; r < 4; r++) inv[r] = 1.0f / l_run[r];
#pragma unroll
    for (int dt = 0; dt < 16; dt++)
#pragma unroll
        for (int r = 0; r < 4; r++) {
            int s = qrow + quad * 4 + r;
            att[((size_t)b * 2048 + s) * 4096 + h * 256 + dt * 16 + l15] = f2b(O[dt][r] * inv[r]);
        }
}

extern "C" void kernel_launch(void* const* d_in, const int* in_sizes, int n_in,
                              void* d_out, int out_size, void* d_ws, size_t ws_size,
                              hipStream_t stream)
{
    const void* hidden  = d_in[0];
    const int*  pos_ids = (const int*)d_in[1];
    const void* w_qkv   = d_in[3];
    const void* w_out   = d_in[4];

    char* ws = (char*)d_ws;
    int* flag   = (int*)ws;
    u16* qbuf   = (u16*)(ws + 256);
    u16* kbuf   = (u16*)(ws + 256 + 33554432ull);
    u16* vbuf   = (u16*)(ws + 256 + 67108864ull);
    u16* att    = (u16*)(ws + 256 + 100663296ull);
    u16* hbuf   = (u16*)(ws + 256 + 134217728ull);   // hidden bf16 [4096,4096]
    u16* wqkvT  = (u16*)(ws + 256 + 167772160ull);   // [12288,4096] bf16
    u16* woutT  = (u16*)(ws + 256 + 268435456ull);   // [4096,4096] bf16

    detect_kernel<<<1, 64, 0, stream>>>((const u16*)hidden, flag);
    convert_kernel<<<8192, 256, 0, stream>>>(hidden, flag, hbuf, 2097152);
    dim3 gt1(12288 / 64, 4096 / 64);
    transpose_conv_kernel<<<gt1, 256, 0, stream>>>(w_qkv, flag, 4096, 12288, wqkvT);
    dim3 gt2(4096 / 64, 4096 / 64);
    transpose_conv_kernel<<<gt2, 256, 0, stream>>>(w_out, flag, 4096, 4096, woutT);

    dim3 g1(12288 / 128, 4096 / 128);
    gemm_bt_kernel<<<g1, 256, 0, stream>>>(hbuf, wqkvT, flag, 4096, 12288, 4096,
                                           1, qbuf, kbuf, vbuf, nullptr);
    rope_kernel<<<8192, 256, 0, stream>>>(qbuf, kbuf, pos_ids);
    dim3 ga(32, 32);
    attn_kernel<<<ga, 256, 0, stream>>>(qbuf, kbuf, vbuf, att);
    dim3 g2(4096 / 128, 4096 / 128);
    gemm_bt_kernel<<<g2, 256, 0, stream>>>(att, woutT, flag, 4096, 4096, 4096,
                                           0, (u16*)d_out, nullptr, nullptr, (float*)d_out);
}

// Round 4
// 1671.728 us; speedup vs baseline: 2.3851x; 1.5148x over previous
//
#include <hip/hip_runtime.h>
#include <hip/hip_bf16.h>
#include <math.h>
#include <stdint.h>

// CodeGenAttention: B=2, S=2048, H=4096, NH=16, D=256, ROT=64, MP=4
// detect dtype -> convert/transpose to bf16 -> QKV GEMM (V stored transposed
// [b,h,d,s]) -> rope -> flash attn (swizzled LDS, 128q x 32k tiles, balanced
// grid) -> out GEMM.

typedef __attribute__((ext_vector_type(8))) short bf16x8;
typedef __attribute__((ext_vector_type(4))) float f32x4;
typedef unsigned short u16;

__device__ __forceinline__ u16 f2b(float f) {
    __hip_bfloat16 h = __float2bfloat16(f);
    return *reinterpret_cast<u16*>(&h);
}
__device__ __forceinline__ float b2f(u16 u) {
    __hip_bfloat16 h = *reinterpret_cast<__hip_bfloat16*>(&u);
    return __bfloat162float(h);
}

__device__ __forceinline__ void load_lds16(const u16* g, u16* l) {
    __builtin_amdgcn_global_load_lds((const __attribute__((address_space(1))) void*)g,
                                     (__attribute__((address_space(3))) void*)l, 16, 0, 0);
}

// ---------------- dtype probe ---------------------------------------------
__global__ void detect_kernel(const u16* __restrict__ h, int* __restrict__ flag)
{
    int lane = threadIdx.x & 63;
    int cnt = 0;
    for (int i = lane; i < 8192; i += 64) {
        int e = (h[i] >> 7) & 0xFF;
        cnt += (e >= 0xC0);
    }
    for (int off = 32; off > 0; off >>= 1) cnt += __shfl_down(cnt, off, 64);
    if (lane == 0) *flag = (cnt > 0) ? 1 : 0;
}

// ---------------- elementwise convert to bf16 (8 elems/thread) ------------
__global__ __launch_bounds__(256)
void convert_kernel(const void* __restrict__ in, const int* __restrict__ flag,
                    u16* __restrict__ outp, int n8)
{
    int idx = blockIdx.x * 256 + threadIdx.x;
    if (idx >= n8) return;
    if (*flag) {
        const float* x = (const float*)in;
        f32x4 a = *reinterpret_cast<const f32x4*>(&x[(size_t)idx * 8]);
        f32x4 b = *reinterpret_cast<const f32x4*>(&x[(size_t)idx * 8 + 4]);
        u16 t[8];
#pragma unroll
        for (int j = 0; j < 4; j++) { t[j] = f2b(a[j]); t[4 + j] = f2b(b[j]); }
        *reinterpret_cast<uint4*>(&outp[(size_t)idx * 8]) = *reinterpret_cast<uint4*>(t);
    } else {
        ((uint4*)outp)[idx] = ((const uint4*)in)[idx];
    }
}

// ---------------- transpose + convert: W[K,N] -> Wt[N,K] bf16 -------------
__global__ __launch_bounds__(256)
void transpose_conv_kernel(const void* __restrict__ Wv, const int* __restrict__ flag,
                           int K, int N, u16* __restrict__ Wt)
{
    __shared__ u16 T[64][68];
    const int tid = threadIdx.x;
    const int k0 = blockIdx.y * 64, n0 = blockIdx.x * 64;
    const int kr = tid >> 4, nc = tid & 15;
    if (*flag) {
        const float* W = (const float*)Wv;
#pragma unroll
        for (int kk = 0; kk < 4; kk++) {
            int k = kr + kk * 16;
            f32x4 v = *reinterpret_cast<const f32x4*>(&W[(size_t)(k0 + k) * N + n0 + nc * 4]);
#pragma unroll
            for (int j = 0; j < 4; j++) T[nc * 4 + j][k] = f2b(v[j]);
        }
    } else {
        const u16* W = (const u16*)Wv;
#pragma unroll
        for (int kk = 0; kk < 4; kk++) {
            int k = kr + kk * 16;
            ushort4 v = *reinterpret_cast<const ushort4*>(&W[(size_t)(k0 + k) * N + n0 + nc * 4]);
            T[nc * 4 + 0][k] = v.x; T[nc * 4 + 1][k] = v.y;
            T[nc * 4 + 2][k] = v.z; T[nc * 4 + 3][k] = v.w;
        }
    }
    __syncthreads();
#pragma unroll
    for (int it = 0; it < 2; it++) {
        int ch = tid + it * 256;
        int n = ch >> 3, kc = ch & 7;
        const uint2* s2 = reinterpret_cast<const uint2*>(&T[n][kc * 8]);
        uint2 a = s2[0], b = s2[1];
        uint4 o; o.x = a.x; o.y = a.y; o.z = b.x; o.w = b.y;
        *reinterpret_cast<uint4*>(&Wt[(size_t)(n0 + n) * K + k0 + kc * 8]) = o;
    }
}

// ---------------- GEMM: C[M,N] = A[M,K] @ Bt[N,K]^T, all bf16 -------------
// m97 structure. mode 0: plain store. mode 1: qkv scatter, V transposed.
__global__ __launch_bounds__(256)
void gemm_bt_kernel(const u16* __restrict__ A, const u16* __restrict__ Bt,
                    const int* __restrict__ flag,
                    int M, int N, int K, int mode,
                    u16* __restrict__ C0, u16* __restrict__ Ck, u16* __restrict__ Cv,
                    float* __restrict__ C0f)
{
    __shared__ u16 As[128][32];
    __shared__ u16 Bs[128][32];

    const int tid  = threadIdx.x;
    const int wave = tid >> 6, lane = tid & 63;
    const int l15  = lane & 15, quad = lane >> 4;
    const int wr   = wave >> 1, wc = wave & 1;
    const int m0   = blockIdx.y * 128, n0 = blockIdx.x * 128;

    const int rsub = lane >> 2;
    const int kc8  = (lane & 3) * 8;

    f32x4 acc[4][4];
#pragma unroll
    for (int i = 0; i < 4; i++)
#pragma unroll
        for (int j = 0; j < 4; j++) acc[i][j] = (f32x4){0.f, 0.f, 0.f, 0.f};

    for (int k0 = 0; k0 < K; k0 += 32) {
#pragma unroll
        for (int t = 0; t < 2; t++) {
            int chunk = wave * 2 + t;
            int row = chunk * 16 + rsub;
            load_lds16(&A[(size_t)(m0 + row) * K + k0 + kc8],  &As[0][0] + chunk * 512);
            load_lds16(&Bt[(size_t)(n0 + row) * K + k0 + kc8], &Bs[0][0] + chunk * 512);
        }
        __syncthreads();

        bf16x8 aF[4], bF[4];
#pragma unroll
        for (int i = 0; i < 4; i++)
            aF[i] = *reinterpret_cast<const bf16x8*>(&As[wr * 64 + i * 16 + l15][quad * 8]);
#pragma unroll
        for (int j = 0; j < 4; j++)
            bF[j] = *reinterpret_cast<const bf16x8*>(&Bs[wc * 64 + j * 16 + l15][quad * 8]);
#pragma unroll
        for (int i = 0; i < 4; i++)
#pragma unroll
            for (int j = 0; j < 4; j++)
                acc[i][j] = __builtin_amdgcn_mfma_f32_16x16x32_bf16(aF[i], bF[j], acc[i][j], 0, 0, 0);
        __syncthreads();
    }

    const int isF32 = *flag;
    if (mode == 0) {
#pragma unroll
        for (int j = 0; j < 4; j++) {
            int n = n0 + wc * 64 + j * 16 + l15;
#pragma unroll
            for (int i = 0; i < 4; i++) {
                int m = m0 + wr * 64 + i * 16 + quad * 4;
#pragma unroll
                for (int r = 0; r < 4; r++) {
                    float v = acc[i][j][r];
                    if (isF32) C0f[(size_t)(m + r) * N + n] = v;
                    else       C0[(size_t)(m + r) * N + n] = f2b(v);
                }
            }
        }
    } else {
        // fused_qkv col n -> (mp group g, third t in {q,v,k}, head, d)
        // Q,K: [b,h,s,d]; V: [b,h,d,s] (transposed for attention B-frags)
#pragma unroll
        for (int j = 0; j < 4; j++) {
            int n = n0 + wc * 64 + j * 16 + l15;
            int g = n / 3072;
            int r3 = n - g * 3072;
            int t = r3 >> 10;            // 0=q, 1=v, 2=k (reference split order)
            int r1 = r3 & 1023;
            int head = g * 4 + (r1 >> 8);
            int d = r1 & 255;
#pragma unroll
            for (int i = 0; i < 4; i++) {
                int m = m0 + wr * 64 + i * 16 + quad * 4;
#pragma unroll
                for (int r = 0; r < 4; r++) {
                    int mm = m + r;
                    int bb = mm >> 11, s = mm & 2047;
                    size_t idx;
                    u16* dst;
                    if (t == 1) { dst = Cv; idx = (size_t)bb * 8388608 + (size_t)head * 524288 + (size_t)d * 2048 + s; }
                    else        { dst = (t == 0) ? C0 : Ck;
                                  idx = (size_t)bb * 8388608 + (size_t)head * 524288 + (size_t)s * 256 + d; }
                    dst[idx] = f2b(acc[i][j][r]);
                }
            }
        }
    }
}

// ---------------- RoPE (in-place on Q,K first 64 dims, interleaved pairs) --
__global__ __launch_bounds__(256)
void rope_kernel(u16* __restrict__ Q, u16* __restrict__ Kb, const int* __restrict__ pos_ids)
{
    int idx = blockIdx.x * 256 + threadIdx.x;
    int i = idx & 31;
    int s = (idx >> 5) & 2047;
    int h = (idx >> 16) & 15;
    int b = idx >> 20;
    int pos = pos_ids[b * 2048 + s];
    float freq = __expf(-(float)(2 * i) * (9.210340371976184f / 64.0f));
    float ang = (float)pos * freq;
    float sn = sinf(ang), cs = cosf(ang);
    size_t base = ((size_t)(b * 16 + h) * 2048 + s) * 256 + 2 * i;
    float q0 = b2f(Q[base]), q1 = b2f(Q[base + 1]);
    Q[base]     = f2b(q0 * cs - q1 * sn);
    Q[base + 1] = f2b(q1 * cs + q0 * sn);
    float k0 = b2f(Kb[base]), k1 = b2f(Kb[base + 1]);
    Kb[base]     = f2b(k0 * cs - k1 * sn);
    Kb[base + 1] = f2b(k1 * cs + k0 * sn);
}

// ---------------- Flash attention (causal) --------------------------------
// Block = 128 q-rows of one (b,h); wave = 32 q-rows (2 m-tiles); k-tile = 32.
// K, Vt staged via global_load_lds into XOR-swizzled LDS (conflict-free b128).
// Grid: 512 blocks, heavy-half-first so each CU's 2 resident blocks sum to
// constant work.
__global__ __launch_bounds__(256, 2)
void attn_kernel(const u16* __restrict__ Q, const u16* __restrict__ Kb,
                 const u16* __restrict__ Vt, u16* __restrict__ att)
{
    __shared__ u16 Ks[32 * 256];    // row=key (32 chunks of 16B), chunk c at p=(c&24)|((c^row)&7)
    __shared__ u16 Vts[256 * 32];   // row=d (4 chunks), chunk c at p=c^((d>>1)&3)
    __shared__ u16 Ps[4][32][40];   // per-wave P [q][k], pitch 40

    const int tid = threadIdx.x;
    const int wave = tid >> 6, lane = tid & 63;
    const int l15 = lane & 15, quad = lane >> 4;

    const int blk = blockIdx.x;
    const int bh = blk & 31;
    const int jj = blk >> 5;
    const int qt = (jj < 8) ? (15 - jj) : (jj - 8);   // heavy-first pairing
    const int b = bh >> 4, h = bh & 15;
    const int qrow = qt * 128 + wave * 32;

    const u16* qb = Q + (size_t)bh * 524288;
    const u16* kb = Kb + (size_t)bh * 524288;
    const u16* vb = Vt + (size_t)bh * 524288;   // [d][s]

    bf16x8 qf[2][8];
#pragma unroll
    for (int mi = 0; mi < 2; mi++)
#pragma unroll
        for (int ks = 0; ks < 8; ks++)
            qf[mi][ks] = *reinterpret_cast<const bf16x8*>(
                &qb[(size_t)(qrow + mi * 16 + l15) * 256 + ks * 32 + quad * 8]);

    f32x4 O[2][16];
#pragma unroll
    for (int mi = 0; mi < 2; mi++)
#pragma unroll
        for (int dt = 0; dt < 16; dt++) O[mi][dt] = (f32x4){0.f, 0.f, 0.f, 0.f};
    float m_run[2][4], l_run[2][4];
#pragma unroll
    for (int mi = 0; mi < 2; mi++)
#pragma unroll
        for (int r = 0; r < 4; r++) { m_run[mi][r] = -1e30f; l_run[mi][r] = 0.f; }
    const float scale = 1.0f / 16.0f;

    const int nkt = qt * 4 + 4;
    for (int kt = 0; kt < nkt; kt++) {
        const int k0 = kt * 32;
#pragma unroll
        for (int t = 0; t < 4; t++) {
            int pc = wave * 256 + t * 64 + lane;
            int rk = pc >> 5, pk = pc & 31;
            int ck = (pk & 24) | ((pk ^ rk) & 7);
            load_lds16(&kb[(size_t)(k0 + rk) * 256 + ck * 8], &Ks[pc * 8]);
            int dv = pc >> 2, pv2 = pc & 3;
            int cv = pv2 ^ ((dv >> 1) & 3);
            load_lds16(&vb[(size_t)dv * 2048 + k0 + cv * 8], &Vts[pc * 8]);
        }
        __syncthreads();

        if (k0 <= qrow + 31) {   // wave-uniform guard
            f32x4 sc[2][2];
#pragma unroll
            for (int mi = 0; mi < 2; mi++)
#pragma unroll
                for (int nt = 0; nt < 2; nt++) sc[mi][nt] = (f32x4){0.f, 0.f, 0.f, 0.f};
#pragma unroll
            for (int ks = 0; ks < 8; ks++)
#pragma unroll
                for (int nt = 0; nt < 2; nt++) {
                    int row = nt * 16 + l15;
                    int c = ks * 4 + quad;
                    int p = (c & 24) | ((c ^ row) & 7);
                    bf16x8 kf = *reinterpret_cast<const bf16x8*>(&Ks[row * 256 + p * 8]);
                    sc[0][nt] = __builtin_amdgcn_mfma_f32_16x16x32_bf16(qf[0][ks], kf, sc[0][nt], 0, 0, 0);
                    sc[1][nt] = __builtin_amdgcn_mfma_f32_16x16x32_bf16(qf[1][ks], kf, sc[1][nt], 0, 0, 0);
                }

#pragma unroll
            for (int mi = 0; mi < 2; mi++) {
                float pw[2][4], mloc[4], alpha[4], sum[4];
#pragma unroll
                for (int r = 0; r < 4; r++) {
                    int qg = qrow + mi * 16 + quad * 4 + r;
#pragma unroll
                    for (int nt = 0; nt < 2; nt++) {
                        int kg = k0 + nt * 16 + l15;
                        float v = sc[mi][nt][r] * scale;
                        pw[nt][r] = (kg <= qg) ? v : -1e30f;
                    }
                    mloc[r] = fmaxf(pw[0][r], pw[1][r]);
                }
#pragma unroll
                for (int off = 1; off < 16; off <<= 1)
#pragma unroll
                    for (int r = 0; r < 4; r++)
                        mloc[r] = fmaxf(mloc[r], __shfl_xor(mloc[r], off, 16));
#pragma unroll
                for (int r = 0; r < 4; r++) {
                    float mnew = fmaxf(m_run[mi][r], mloc[r]);
                    alpha[r] = __expf(m_run[mi][r] - mnew);
                    pw[0][r] = __expf(pw[0][r] - mnew);
                    pw[1][r] = __expf(pw[1][r] - mnew);
                    sum[r] = pw[0][r] + pw[1][r];
                    m_run[mi][r] = mnew;
                }
#pragma unroll
                for (int off = 1; off < 16; off <<= 1)
#pragma unroll
                    for (int r = 0; r < 4; r++)
                        sum[r] += __shfl_xor(sum[r], off, 16);
#pragma unroll
                for (int r = 0; r < 4; r++) l_run[mi][r] = l_run[mi][r] * alpha[r] + sum[r];
#pragma unroll
                for (int dt = 0; dt < 16; dt++)
#pragma unroll
                    for (int r = 0; r < 4; r++) O[mi][dt][r] *= alpha[r];
#pragma unroll
                for (int nt = 0; nt < 2; nt++)
#pragma unroll
                    for (int r = 0; r < 4; r++)
                        Ps[wave][mi * 16 + quad * 4 + r][nt * 16 + l15] = f2b(pw[nt][r]);
            }
            bf16x8 aP0 = *reinterpret_cast<const bf16x8*>(&Ps[wave][l15][quad * 8]);
            bf16x8 aP1 = *reinterpret_cast<const bf16x8*>(&Ps[wave][16 + l15][quad * 8]);
#pragma unroll
            for (int dt = 0; dt < 16; dt++) {
                int d = dt * 16 + l15;
                int pch = quad ^ ((d >> 1) & 3);
                bf16x8 vf = *reinterpret_cast<const bf16x8*>(&Vts[d * 32 + pch * 8]);
                O[0][dt] = __builtin_amdgcn_mfma_f32_16x16x32_bf16(aP0, vf, O[0][dt], 0, 0, 0);
                O[1][dt] = __builtin_amdgcn_mfma_f32_16x16x32_bf16(aP1, vf, O[1][dt], 0, 0, 0);
            }
        }
        __syncthreads();
    }

#pragma unroll
    for (int mi = 0; mi < 2; mi++) {
        float inv[4];
#pragma unroll
        for (int r = 0; r < 4; r++) inv[r] = 1.0f / l_run[mi][r];
#pragma unroll
        for (int dt = 0; dt < 16; dt++)
#pragma unroll
            for (int r = 0; r < 4; r++) {
                int s = qrow + mi * 16 + quad * 4 + r;
                att[((size_t)b * 2048 + s) * 4096 + h * 256 + dt * 16 + l15] =
                    f2b(O[mi][dt][r] * inv[r]);
            }
    }
}

extern "C" void kernel_launch(void* const* d_in, const int* in_sizes, int n_in,
                              void* d_out, int out_size, void* d_ws, size_t ws_size,
                              hipStream_t stream)
{
    const void* hidden  = d_in[0];
    const int*  pos_ids = (const int*)d_in[1];
    const void* w_qkv   = d_in[3];
    const void* w_out   = d_in[4];

    char* ws = (char*)d_ws;
    int* flag   = (int*)ws;
    u16* qbuf   = (u16*)(ws + 256);
    u16* kbuf   = (u16*)(ws + 256 + 33554432ull);
    u16* vbuf   = (u16*)(ws + 256 + 67108864ull);          // [b,h,d,s]
    u16* att    = (u16*)(ws + 256 + 100663296ull);
    u16* hbuf   = (u16*)(ws + 256 + 134217728ull);
    u16* wqkvT  = (u16*)(ws + 256 + 167772160ull);
    u16* woutT  = (u16*)(ws + 256 + 268435456ull);

    detect_kernel<<<1, 64, 0, stream>>>((const u16*)hidden, flag);
    convert_kernel<<<8192, 256, 0, stream>>>(hidden, flag, hbuf, 2097152);
    dim3 gt1(12288 / 64, 4096 / 64);
    transpose_conv_kernel<<<gt1, 256, 0, stream>>>(w_qkv, flag, 4096, 12288, wqkvT);
    dim3 gt2(4096 / 64, 4096 / 64);
    transpose_conv_kernel<<<gt2, 256, 0, stream>>>(w_out, flag, 4096, 4096, woutT);

    dim3 g1(12288 / 128, 4096 / 128);
    gemm_bt_kernel<<<g1, 256, 0, stream>>>(hbuf, wqkvT, flag, 4096, 12288, 4096,
                                           1, qbuf, kbuf, vbuf, nullptr);
    rope_kernel<<<8192, 256, 0, stream>>>(qbuf, kbuf, pos_ids);
    attn_kernel<<<512, 256, 0, stream>>>(qbuf, kbuf, vbuf, att);
    dim3 g2(4096 / 128, 4096 / 128);
    gemm_bt_kernel<<<g2, 256, 0, stream>>>(att, woutT, flag, 4096, 4096, 4096,
                                           0, (u16*)d_out, nullptr, nullptr, (float*)d_out);
}